// Round 3
// baseline (43124.741 us; speedup 1.0000x reference)
//
#include <hip/hip_runtime.h>
#include <stdint.h>

#define B_ 64
#define S_ 512
#define I_ 1024
#define H_ 1024

typedef __attribute__((ext_vector_type(8))) short bf16x8;
typedef __attribute__((ext_vector_type(4))) float f32x4;

// ---- workspace layout (bytes). All fp32 values carried as bf16 hi/lo planes.
#define BAR_OFF   0u                     // 4 KB: 4 group counters, 256B apart
#define BIAS_OFF  4096u                  // 16 KB fp32[4096] (bih+bhh)
#define XT_OFF    32768u                 // 2 x 128 KB bf16[64][1024] hi,lo
#define HT0_OFF   (XT_OFF + 262144u)
#define HT1_OFF   (HT0_OFF + 262144u)
#define QT_OFF    (1u << 20)             // 2 x 2 MB  Qt[n][k]=Q[k][n] hi,lo
#define RT_OFF    (5u << 20)             // 2 x 2 MB
#define GT_OFF    (9u << 20)             // 2 x 16 MB Gt[n][k]={Wih|Whh}[k][n] hi,lo
#define APLANE    65536                  // activation plane stride (elements)
#define QPLANE    (1024 * 1024)          // Q/R plane stride (elements)
#define GPLANE    (4096 * 2048)          // G plane stride (elements)

__device__ inline float bf2f(uint16_t u) {
    uint32_t v = ((uint32_t)u) << 16; float f; __builtin_memcpy(&f, &v, 4); return f;
}
__device__ inline uint16_t f2bf(float f) {
    uint32_t v; __builtin_memcpy(&v, &f, 4);
    v = (v + 0x7FFFu + ((v >> 16) & 1u)) >> 16;   // round-to-nearest-even
    return (uint16_t)v;
}
__device__ inline void f2hilo(float v, uint16_t& hi, uint16_t& lo) {
    hi = f2bf(v);
    lo = f2bf(v - bf2f(hi));
}
__device__ inline float sigmf(float x) { return 1.0f / (1.0f + __expf(-x)); }

// dst[n][k] = src[k][n] as bf16 hi/lo planes; src fp32 row-major [.,N]
__global__ __launch_bounds__(256)
void transpose_f32(const float* __restrict__ src, uint16_t* __restrict__ dstHi,
                   uint16_t* __restrict__ dstLo, int N, int dstStride, int dstColOff)
{
    __shared__ float tile[64][65];
    int k0 = blockIdx.x * 64;
    int n0 = blockIdx.y * 64;
    for (int i = threadIdx.x; i < 4096; i += 256) {
        int rr = i >> 6, cc = i & 63;
        tile[rr][cc] = src[(int64_t)(k0 + rr) * N + n0 + cc];
    }
    __syncthreads();
    for (int i = threadIdx.x; i < 4096; i += 256) {
        int rr = i >> 6, cc = i & 63;
        float v = tile[cc][rr];
        uint16_t hi, lo; f2hilo(v, hi, lo);
        int64_t o = (int64_t)(n0 + rr) * dstStride + dstColOff + k0 + cc;
        dstHi[o] = hi; dstLo[o] = lo;
    }
}

__global__ __launch_bounds__(256)
void bias_kernel(const float* __restrict__ a, const float* __restrict__ b,
                 float* __restrict__ o)
{
    int i = blockIdx.x * 256 + threadIdx.x;
    if (i < 4096) o[i] = a[i] + b[i];
}

// Persistent mogrifier-LSTM. 256 WGs = 4 row-groups (16 batch rows each,
// independent barrier domains) x 64 col-slices (16 cols). blk->(r,c) keeps a
// column's 4 row-WGs and adjacent slices on one XCD.
__global__ __launch_bounds__(256, 1)
void mog_lstm(const float* __restrict__ x,
              const float* __restrict__ h0,
              const float* __restrict__ c0,
              const uint16_t* __restrict__ Qt,   // hi plane; lo at +QPLANE
              const uint16_t* __restrict__ Rt,
              const uint16_t* __restrict__ Gt,   // hi plane; lo at +GPLANE
              const float*    __restrict__ biasf,
              uint16_t* __restrict__ xtb,        // hi plane; lo at +APLANE
              uint16_t* __restrict__ ht0b,
              uint16_t* __restrict__ ht1b,
              uint32_t* __restrict__ bar,
              float* __restrict__ out)
{
    const int tid  = threadIdx.x;
    const int lane = tid & 63;
    const int wave = tid >> 6;
    const int blk  = blockIdx.x;
    const int r    = (blk >> 3) & 3;             // row group 0..3
    const int c    = (blk & 7) * 8 + (blk >> 5); // col slice 0..63 (XCD-blocked)
    const int q4   = lane >> 4;
    const int cl   = lane & 15;
    const int kOff = q4 * 8;

    __shared__ float part[4][16][16];
    __shared__ float Ct_s[16][16];

    uint32_t* cnt = bar + r * 64;
    uint32_t bt = 0;
    const uint64_t t0c = __builtin_amdgcn_s_memrealtime();

    auto gbar = [&]() {
        bt += 64;
        __syncthreads();
        if (tid == 0) {
            __builtin_amdgcn_fence(__ATOMIC_RELEASE, "agent");
            __hip_atomic_fetch_add(cnt, 1u, __ATOMIC_RELAXED, __HIP_MEMORY_SCOPE_AGENT);
            while (__hip_atomic_load(cnt, __ATOMIC_RELAXED, __HIP_MEMORY_SCOPE_AGENT) < bt) {
                __builtin_amdgcn_s_sleep(2);
                if (__builtin_amdgcn_s_memrealtime() - t0c > 400000000ull) break; // watchdog
            }
            __builtin_amdgcn_fence(__ATOMIC_ACQUIRE, "agent");
        }
        __syncthreads();
    };

    // u = A(rows 16r..) @ Wt(rows 16c..)^T, K=1024 split over 4 waves, split-bf16;
    // then new = 2*sigmoid(u) * old (own slice). gF!=null: old from fp32 global.
    auto mogp = [&](const uint16_t* __restrict__ Ahi, const uint16_t* __restrict__ Whi,
                    const float* gF, int64_t gFs, uint16_t* gHi) {
        const int64_t aoff = (int64_t)(r * 16 + cl) * 1024 + wave * 256 + kOff;
        const int64_t boff = (int64_t)(c * 16 + cl) * 1024 + wave * 256 + kOff;
        const uint16_t* ah = Ahi + aoff;
        const uint16_t* al = Ahi + APLANE + aoff;
        const uint16_t* bh = Whi + boff;
        const uint16_t* bl = Whi + QPLANE + boff;
        f32x4 acc = {0.f, 0.f, 0.f, 0.f};
#pragma unroll
        for (int k = 0; k < 256; k += 32) {
            bf16x8 vah = *(const bf16x8*)(ah + k);
            bf16x8 val = *(const bf16x8*)(al + k);
            bf16x8 vbh = *(const bf16x8*)(bh + k);
            bf16x8 vbl = *(const bf16x8*)(bl + k);
            acc = __builtin_amdgcn_mfma_f32_16x16x32_bf16(vah, vbh, acc, 0, 0, 0);
            acc = __builtin_amdgcn_mfma_f32_16x16x32_bf16(vah, vbl, acc, 0, 0, 0);
            acc = __builtin_amdgcn_mfma_f32_16x16x32_bf16(val, vbh, acc, 0, 0, 0);
        }
#pragma unroll
        for (int i = 0; i < 4; ++i) part[wave][q4 * 4 + i][cl] = acc[i];
        __syncthreads();
        if (wave == 0) {
#pragma unroll
            for (int i = 0; i < 4; ++i) {
                int row = q4 * 4 + i;
                float u = part[0][row][cl] + part[1][row][cl]
                        + part[2][row][cl] + part[3][row][cl];
                float gm = 2.0f * sigmf(u);
                float oldv;
                if (gF) oldv = gF[(int64_t)row * gFs + cl];
                else    oldv = bf2f(gHi[row * 1024 + cl]) + bf2f(gHi[APLANE + row * 1024 + cl]);
                float nv = gm * oldv;
                uint16_t hi, lo; f2hilo(nv, hi, lo);
                gHi[row * 1024 + cl] = hi;
                gHi[APLANE + row * 1024 + cl] = lo;
            }
        }
    };

    // init: ht0 = h0 (hi/lo), Ct_s = c0 (fp32), own slice
    if (wave == 0) {
#pragma unroll
        for (int i = 0; i < 4; ++i) {
            int row = q4 * 4 + i;
            int grow = r * 16 + row, gcol = c * 16 + cl;
            uint16_t hi, lo; f2hilo(h0[grow * 1024 + gcol], hi, lo);
            ht0b[grow * 1024 + gcol] = hi;
            ht0b[APLANE + grow * 1024 + gcol] = lo;
            Ct_s[row][cl] = c0[grow * 1024 + gcol];
        }
    }
    gbar();

    for (int t = 0; t < S_; ++t) {
        const int p = t & 1;
        uint16_t* htp = p ? ht1b : ht0b;   // ht for this step
        uint16_t* htn = p ? ht0b : ht1b;   // ht_new parity
        uint16_t* xsl = xtb + (r * 16) * 1024 + c * 16;
        uint16_t* hsl = htp + (r * 16) * 1024 + c * 16;
        const float* xsrc = x + (int64_t)(r * 16) * (S_ * I_) + (int64_t)t * I_ + c * 16;

        mogp(htp, Qt, xsrc, (int64_t)S_ * I_, xsl); gbar(); // xt1 = 2s(ht0@Q)*x_t
        mogp(xtb, Rt, nullptr, 0, hsl);             gbar(); // ht1 = 2s(xt1@R)*ht0
        mogp(htp, Qt, nullptr, 0, xsl);             gbar(); // xt2 = 2s(ht1@Q)*xt1
        mogp(xtb, Rt, nullptr, 0, hsl);             gbar(); // ht2 = 2s(xt2@R)*ht1

        // ---- P5: gates = [xt2|ht2] @ Gt^T + bias, then LSTM cell ----
        const int colB = wave * 1024 + c * 16 + cl;  // wave = gate quadrant (i,f,g,o)
        const int64_t arow = (int64_t)(r * 16 + cl) * 1024 + kOff;
        const uint16_t* axh = xtb + arow;
        const uint16_t* axl = xtb + APLANE + arow;
        const uint16_t* ahh = htp + arow;
        const uint16_t* ahl = htp + APLANE + arow;
        const uint16_t* bh = Gt + (int64_t)colB * 2048 + kOff;
        const uint16_t* bl = Gt + GPLANE + (int64_t)colB * 2048 + kOff;
        f32x4 acc = {0.f, 0.f, 0.f, 0.f};
#pragma unroll 4
        for (int k = 0; k < 1024; k += 32) {
            bf16x8 vah = *(const bf16x8*)(axh + k);
            bf16x8 val = *(const bf16x8*)(axl + k);
            bf16x8 vbh = *(const bf16x8*)(bh + k);
            bf16x8 vbl = *(const bf16x8*)(bl + k);
            acc = __builtin_amdgcn_mfma_f32_16x16x32_bf16(vah, vbh, acc, 0, 0, 0);
            acc = __builtin_amdgcn_mfma_f32_16x16x32_bf16(vah, vbl, acc, 0, 0, 0);
            acc = __builtin_amdgcn_mfma_f32_16x16x32_bf16(val, vbh, acc, 0, 0, 0);
        }
#pragma unroll 4
        for (int k = 0; k < 1024; k += 32) {
            bf16x8 vah = *(const bf16x8*)(ahh + k);
            bf16x8 val = *(const bf16x8*)(ahl + k);
            bf16x8 vbh = *(const bf16x8*)(bh + 1024 + k);
            bf16x8 vbl = *(const bf16x8*)(bl + 1024 + k);
            acc = __builtin_amdgcn_mfma_f32_16x16x32_bf16(vah, vbh, acc, 0, 0, 0);
            acc = __builtin_amdgcn_mfma_f32_16x16x32_bf16(vah, vbl, acc, 0, 0, 0);
            acc = __builtin_amdgcn_mfma_f32_16x16x32_bf16(val, vbh, acc, 0, 0, 0);
        }
        {
            float bb = biasf[colB];
            acc[0] += bb; acc[1] += bb; acc[2] += bb; acc[3] += bb;
        }
#pragma unroll
        for (int i = 0; i < 4; ++i) part[wave][q4 * 4 + i][cl] = acc[i];
        __syncthreads();
        if (wave == 0) {
#pragma unroll
            for (int i = 0; i < 4; ++i) {
                int row = q4 * 4 + i;
                float gi = part[0][row][cl], gf = part[1][row][cl];
                float gg = part[2][row][cl], go = part[3][row][cl];
                float ii = sigmf(gi), ff = sigmf(gf);
                float g2 = tanhf(gg), oo = sigmf(go);
                float Cn = ff * Ct_s[row][cl] + ii * g2;
                float hh = oo * tanhf(Cn);
                Ct_s[row][cl] = Cn;
                int grow = r * 16 + row, gcol = c * 16 + cl;
                uint16_t hi, lo; f2hilo(hh, hi, lo);
                htn[grow * 1024 + gcol] = hi;
                htn[APLANE + grow * 1024 + gcol] = lo;
                out[(int64_t)grow * (S_ * H_) + (int64_t)t * H_ + gcol] = hh;
                if (t == S_ - 1)
                    out[(int64_t)B_ * S_ * H_ + grow * H_ + gcol] = hh;
            }
        }
        gbar();
    }

    if (wave == 0) {
#pragma unroll
        for (int i = 0; i < 4; ++i) {
            int row = q4 * 4 + i;
            int grow = r * 16 + row, gcol = c * 16 + cl;
            out[(int64_t)B_ * S_ * H_ + (int64_t)B_ * H_ + grow * H_ + gcol] = Ct_s[row][cl];
        }
    }
}

extern "C" void kernel_launch(void* const* d_in, const int* in_sizes, int n_in,
                              void* d_out, int out_size, void* d_ws, size_t ws_size,
                              hipStream_t stream)
{
    (void)in_sizes; (void)n_in; (void)out_size; (void)ws_size;
    const float* x   = (const float*)d_in[0];
    const float* h0  = (const float*)d_in[1];
    const float* c0  = (const float*)d_in[2];
    const float* Wih = (const float*)d_in[3];
    const float* Whh = (const float*)d_in[4];
    const float* bih = (const float*)d_in[5];
    const float* bhh = (const float*)d_in[6];
    const float* Q   = (const float*)d_in[7];
    const float* R   = (const float*)d_in[8];

    char* ws = (char*)d_ws;
    uint32_t* bar   = (uint32_t*)(ws + BAR_OFF);
    float*    biasf = (float*)(ws + BIAS_OFF);
    uint16_t* xtb   = (uint16_t*)(ws + XT_OFF);
    uint16_t* ht0b  = (uint16_t*)(ws + HT0_OFF);
    uint16_t* ht1b  = (uint16_t*)(ws + HT1_OFF);
    uint16_t* Qt    = (uint16_t*)(ws + QT_OFF);
    uint16_t* Rt    = (uint16_t*)(ws + RT_OFF);
    uint16_t* Gt    = (uint16_t*)(ws + GT_OFF);

    (void)hipMemsetAsync(ws + BAR_OFF, 0, 4096, stream);
    bias_kernel<<<16, 256, 0, stream>>>(bih, bhh, biasf);
    transpose_f32<<<dim3(16, 16), 256, 0, stream>>>(Q,   Qt, Qt + QPLANE, 1024, 1024, 0);
    transpose_f32<<<dim3(16, 16), 256, 0, stream>>>(R,   Rt, Rt + QPLANE, 1024, 1024, 0);
    transpose_f32<<<dim3(16, 64), 256, 0, stream>>>(Wih, Gt, Gt + GPLANE, 4096, 2048, 0);
    transpose_f32<<<dim3(16, 64), 256, 0, stream>>>(Whh, Gt, Gt + GPLANE, 4096, 2048, 1024);
    mog_lstm<<<256, 256, 0, stream>>>(x, h0, c0, Qt, Rt, Gt, biasf,
                                      xtb, ht0b, ht1b, bar, (float*)d_out);
}